// Round 9
// baseline (90.336 us; speedup 1.0000x reference)
//
#include <hip/hip_runtime.h>

// v15: convoy-breaking via 4 independent barrier domains per CU.
// v14 post-mortem: conflict fix + barrier halving regressed 2 us. Falsified
// for k_proj: ordering (v8), LDS volume (v9/v13), barrier count (v11/v14),
// occupancy (v12, -2.8 only), bank conflicts (v14). Surviving model: CONVOY
// execution -- all waves barrier-locked in the same phase, wall ~= SUM of
// pipe times (v6->v7's -5.5 us == the trans-pipe delta exactly). Lever:
// desync. v15 = 8-wave blocks, grid (NS,B,2); block h owns rows h*64..+63
// (8 tiles, 1/wave). Each block GENs its own gx + its gy half (1.5x exp,
// +~2 us trans -- the probe's price). LDS 37,888 B <= 40 KB -> 4 blocks/CU
// = 4 independent barrier groups interleaving pipe demand. GSTR=36 (2-way
// banks, free), b64 frag ops, launch_bounds(512,8) pins VGPR <= 64.
// Pre-committed falsifier: >= 85 us -> declare roofline, restore v12.

#define S 128
#define NS 32            // K-splits: 31 x 640 + 1 x 160 atoms
#define PER 640
#define BLOCK 512        // 8 waves: tile = (2h + (wav>>2)) * 4 + (wav&3)
#define KC 32            // atoms per chunk (2 MFMA K-steps)
#define GSTR 36          // f16 per position row: 32 atoms + 4 pad (72 B)

typedef _Float16 f16;
typedef _Float16 f16x2 __attribute__((ext_vector_type(2)));
typedef _Float16 f16x4 __attribute__((ext_vector_type(4)));
typedef _Float16 f16x8 __attribute__((ext_vector_type(8)));
typedef float floatx16 __attribute__((ext_vector_type(16)));

#if __has_builtin(__builtin_amdgcn_exp2f)
#define FAST_EXP2(x) __builtin_amdgcn_exp2f(x)
#else
#define FAST_EXP2(x) exp2f(x)
#endif
#if __has_builtin(__builtin_amdgcn_rcpf)
#define FAST_RCP(x) __builtin_amdgcn_rcpf(x)
#else
#define FAST_RCP(x) (1.0f / (x))
#endif

static __device__ __forceinline__ f16x2 PKRTZ(float a, float b) {
#if __has_builtin(__builtin_amdgcn_cvt_pkrtz)
    return __builtin_bit_cast(f16x2, __builtin_amdgcn_cvt_pkrtz(a, b));
#else
    return (f16x2){(f16)a, (f16)b};
#endif
}

union frag_u { f16x8 v; f16x4 q[2]; f16x2 h[4]; };
union half4_u { f16x4 q; f16x2 h[2]; };

struct SharedT {
    float4 sG[PER];              // (x, y, z, w): 10,240 B
    f16 gx[2][S * GSTR];         // [parity][col*GSTR + atom]: 18,432 B
    f16 gy[2][64 * GSTR];        // [parity][(row-h*64)*GSTR + atom]: 9,216 B
};                               // 37,888 B -> 4 blocks/CU, 32 waves/CU

__global__ __launch_bounds__(BLOCK, 8) void k_proj(
    const float* __restrict__ mol,   // (B, A, 3)
    const float* __restrict__ stds,  // (A)
    const float* __restrict__ dens,  // (A)
    f16* __restrict__ part,          // (B*NS, 128*128) f16 partials, frag order
    int B, int A)
{
    __shared__ SharedT sh;

    const int ks   = blockIdx.x;
    const int b    = blockIdx.y;
    const int h    = blockIdx.z;     // image row half: rows h*64 .. h*64+63
    const int tid  = threadIdx.x;
    const int lane = tid & 63;
    const int wav  = tid >> 6;       // 0..7
    const int l31  = lane & 31;
    const int hi   = lane >> 5;

    const int a0  = ks * PER;
    const int a1  = min(a0 + PER, A);
    const int cnt = a1 - a0;          // 640 or 160, both divisible by KC
    const int nc  = cnt >> 5;         // chunks of 32 atoms: 20 or 5

    for (int i = tid; i < cnt; i += BLOCK) {
        const int a = a0 + i;
        const size_t idx = (size_t)b * A + a;
        float x  = mol[idx * 3 + 0];
        float y  = mol[idx * 3 + 1];
        float v  = stds[a] * stds[a];
        float rv = FAST_RCP(v);
        float z  = -0.72134752044448f * rv;                 // -0.5*log2(e)/var
        float w  = __log2f(dens[a] * 0.15915494309189535f * rv);
        sh.sG[i] = make_float4(x, y, z, w);
    }
    __syncthreads();

    // GEN role: wave = 4-atom group (8 x 4 = 32); 3 planes per atom:
    //   gx @ col=lane, gx @ col=lane+64, gy @ row=h*64+lane (carries coef)
    const int agrp  = wav;
    const float cx0 = (float)lane - 63.5f;
    const float cy0 = (float)(h * 64 + lane) - 63.5f;

    // compute role: tile (r = 2h + (wav>>2), c = wav&3)
    const int arow = (wav >> 2) * 32 + l31;   // gy local row
    const int bcol = (wav & 3) * 32 + l31;    // gx col
    const int koff = hi * 8;                  // K-step atom sub-offset

    floatx16 acc = (floatx16){0.f};

    // generate this wave's 4 atoms of chunk c into parity par (12 exps)
    auto GEN_CHUNK = [&](int c, int par) {
        const float4* prm = &sh.sG[c * KC + agrp * 4];   // wave-uniform bcast
        half4_u X0, X1, Y0;
#pragma unroll
        for (int i2 = 0; i2 < 2; ++i2) {
            float ex0[2], ex1[2], ey0[2];
#pragma unroll
            for (int u = 0; u < 2; ++u) {
                float4 p = prm[i2 * 2 + u];      // (x, y, z, w)
                float d  = cx0 - p.x;            // gx pair (cols lane, lane+64)
                float t  = p.z * d;
                float g0 = t * d;
                float g1 = fmaf(128.0f, t, fmaf(4096.0f, p.z, g0));
                ex0[u] = FAST_EXP2(g0);
                ex1[u] = FAST_EXP2(g1);
                float dy = cy0 - p.y;            // gy single (row h*64+lane)
                float ty = p.z * dy;
                ey0[u] = FAST_EXP2(fmaf(ty, dy, p.w));
            }
            X0.h[i2] = PKRTZ(ex0[0], ex0[1]);
            X1.h[i2] = PKRTZ(ex1[0], ex1[1]);
            Y0.h[i2] = PKRTZ(ey0[0], ey0[1]);
        }
        f16* dx = &sh.gx[par][lane * GSTR + agrp * 4];   // 8B-aligned b64s
        *(f16x4*)dx               = X0.q;
        *(f16x4*)(dx + 64 * GSTR) = X1.q;
        f16* dy_ = &sh.gy[par][lane * GSTR + agrp * 4];
        *(f16x4*)dy_ = Y0.q;
    };

    // STEP: consume chunk c from parity P; generate c+1 into P^1 (P^1 was
    // fully consumed before the previous barrier -> safe pre-barrier).
#define STEP(P)                                                                \
    do {                                                                       \
        const f16* gy = sh.gy[(P)];                                            \
        const f16* gx = sh.gx[(P)];                                            \
        const bool gen = (c + 1 < nc);                                         \
        if (gen) GEN_CHUNK(c + 1, (P) ^ 1);                                    \
        _Pragma("unroll")                                                      \
        for (int s = 0; s < 2; ++s) {                                          \
            frag_u Af, Bf;                                                     \
            const f16* ay = gy + arow * GSTR + s * 16 + koff;                  \
            const f16* bx = gx + bcol * GSTR + s * 16 + koff;                  \
            Af.q[0] = *(const f16x4*)(ay);                                     \
            Af.q[1] = *(const f16x4*)(ay + 4);                                 \
            Bf.q[0] = *(const f16x4*)(bx);                                     \
            Bf.q[1] = *(const f16x4*)(bx + 4);                                 \
            acc = __builtin_amdgcn_mfma_f32_32x32x16_f16(Af.v, Bf.v, acc, 0, 0, 0); \
        }                                                                      \
        __syncthreads();                                                       \
        ++c;                                                                   \
    } while (0)

    GEN_CHUNK(0, 0);                  // prologue: chunk 0 into parity 0
    __syncthreads();

    int c = 0;
    while (c + 2 <= nc) { STEP(0); STEP(1); }
    if (c < nc) STEP(0);              // nc odd (tail split): even parity
#undef STEP

    // epilogue: direct store -- wave owns tile (2h + wav>>2, wav&3), full K
    {
        const int tileidx = (2 * h + (wav >> 2)) * 4 + (wav & 3);
        f16* pq = part + ((size_t)(b * NS + ks)) * (S * S)
                       + (size_t)tileidx * 1024 + lane * 16;
        frag_u lo, hiv;
#pragma unroll
        for (int jp = 0; jp < 4; ++jp) {
            lo.h[jp]  = PKRTZ(acc[2 * jp],     acc[2 * jp + 1]);
            hiv.h[jp] = PKRTZ(acc[2 * jp + 8], acc[2 * jp + 9]);
        }
        *(f16x8*)(pq + 0) = lo.v;
        *(f16x8*)(pq + 8) = hiv.v;
    }
}

// sum NS f16 partials per batch: 4 waves/block each sum 8 slices (512 blocks),
// LDS combine, un-permute fragment order, write f32.
__global__ __launch_bounds__(256) void k_reduce(const f16* __restrict__ part,
                                                float* __restrict__ out) {
    __shared__ float lred[3][64][9];   // +1 pad: conflict-free strided stores
    const int b    = blockIdx.z;
    const int lane = threadIdx.x & 63;
    const int w    = threadIdx.x >> 6;
    const int f8   = (blockIdx.x * 64 + lane) * 8;   // frag-order base idx

    const f16* src = part + (size_t)b * NS * (S * S) + (size_t)(w * 8) * (S * S) + f8;
    float s[8] = {0.f};
#pragma unroll
    for (int t = 0; t < 8; ++t) {
        f16x8 v = *(const f16x8*)&src[(size_t)t * (S * S)];
#pragma unroll
        for (int i = 0; i < 8; ++i) s[i] += (float)v[i];
    }

    if (w) {
#pragma unroll
        for (int i = 0; i < 8; ++i) lred[w - 1][lane][i] = s[i];
    }
    __syncthreads();

    if (w == 0) {
#pragma unroll
        for (int j = 0; j < 3; ++j)
#pragma unroll
            for (int i = 0; i < 8; ++i) s[i] += lred[j][lane][i];

        // decode f8 = tile*1024 + lane_f*16 + reg0; tile = r*4 + c (32x32 tiles)
        const int reg0   = f8 & 15;
        const int lane_f = (f8 >> 4) & 63;
        const int tile   = f8 >> 10;
        const int r      = tile >> 2;
        const int cc     = tile & 3;
        // mfma_32x32 C/D: col = lane&31, row = (reg&3) + 8*(reg>>2) + 4*(lane>>5)
        const int rowb = r * 32 + 4 * (lane_f >> 5);
        const int col  = cc * 32 + (lane_f & 31);
#pragma unroll
        for (int i = 0; i < 8; ++i) {
            const int reg = reg0 + i;
            const int row = rowb + (reg & 3) + 8 * (reg >> 2);
            out[((size_t)b * S + row) * S + col] = s[i];
        }
    }
}

extern "C" void kernel_launch(void* const* d_in, const int* in_sizes, int n_in,
                              void* d_out, int out_size, void* d_ws, size_t ws_size,
                              hipStream_t stream) {
    const float* mol  = (const float*)d_in[0];
    const float* stds = (const float*)d_in[1];
    const float* dens = (const float*)d_in[2];
    float* out = (float*)d_out;

    const int A = in_sizes[1];             // 20000
    const int B = in_sizes[0] / (A * 3);   // 16

    f16* part = (f16*)d_ws;                // B*NS*16384*2 = 16 MB

    k_proj<<<dim3(NS, B, 2), dim3(BLOCK), 0, stream>>>(mol, stds, dens, part, B, A);
    k_reduce<<<dim3((S * S) / (64 * 8), 1, B), dim3(256), 0, stream>>>(part, out);
}

// Round 10
// 85.439 us; speedup vs baseline: 1.0573x; 1.0573x over previous
//
#include <hip/hip_runtime.h>

// v12 (FINAL, restored): occupancy doubling via tile-per-wave. Best measured:
// 85.85 us. Subsequent probes all regressed or were neutral: v13 readlane
// params (-7), v14 conflict-free GSTR=68 (-2), v15 4-domain desync (-4.5).
// Budget: fill ~43 us (harness re-poison, memory-bound), k_proj ~36 us
// (tested against ordering/LDS-volume/barriers/occupancy/conflicts/desync --
// all priced), k_reduce ~4 us (~80% HBM). This is the structural floor.

#define S 128
#define NS 32            // K-splits: 31 x 640 + 1 x 160 atoms
#define PER 640
#define BLOCK 1024       // 16 waves: tile = wav (r=wav>>2, c=wav&3)
#define KC 32            // atoms per chunk (2 MFMA K-steps)
#define GSTR 40          // f16 per position row: 32 atoms + 8 pad (80 B)

typedef _Float16 f16;
typedef _Float16 f16x2 __attribute__((ext_vector_type(2)));
typedef _Float16 f16x4 __attribute__((ext_vector_type(4)));
typedef _Float16 f16x8 __attribute__((ext_vector_type(8)));
typedef float floatx16 __attribute__((ext_vector_type(16)));

#if __has_builtin(__builtin_amdgcn_exp2f)
#define FAST_EXP2(x) __builtin_amdgcn_exp2f(x)
#else
#define FAST_EXP2(x) exp2f(x)
#endif
#if __has_builtin(__builtin_amdgcn_rcpf)
#define FAST_RCP(x) __builtin_amdgcn_rcpf(x)
#else
#define FAST_RCP(x) (1.0f / (x))
#endif

static __device__ __forceinline__ f16x2 PKRTZ(float a, float b) {
#if __has_builtin(__builtin_amdgcn_cvt_pkrtz)
    return __builtin_bit_cast(f16x2, __builtin_amdgcn_cvt_pkrtz(a, b));
#else
    return (f16x2){(f16)a, (f16)b};
#endif
}

union frag_u { f16x8 v; f16x4 q[2]; f16x2 h[4]; };
union half4_u { f16x4 q; f16x2 h[2]; };

struct SharedT {
    float4 sG[PER];              // (x, y, z, w): 10,240 B
    f16 g[2][2][S * GSTR];       // [parity][axis][pos*GSTR + atom]: 40,960 B
};                               // 51,200 B -> 2 blocks/CU, 32 waves/CU

__global__ __launch_bounds__(BLOCK, 8) void k_proj(
    const float* __restrict__ mol,   // (B, A, 3)
    const float* __restrict__ stds,  // (A)
    const float* __restrict__ dens,  // (A)
    f16* __restrict__ part,          // (B*NS, 128*128) f16 partials, frag order
    int B, int A)
{
    __shared__ SharedT sh;

    const int ks   = blockIdx.x;
    const int b    = blockIdx.y;
    const int tid  = threadIdx.x;
    const int lane = tid & 63;
    const int wav  = tid >> 6;       // 0..15 = output tile index (r*4 + c)
    const int l31  = lane & 31;
    const int hi   = lane >> 5;

    const int a0  = ks * PER;
    const int a1  = min(a0 + PER, A);
    const int cnt = a1 - a0;          // 640 or 160, both divisible by KC

    for (int i = tid; i < cnt; i += BLOCK) {
        const int a = a0 + i;
        const size_t idx = (size_t)b * A + a;
        float x  = mol[idx * 3 + 0];
        float y  = mol[idx * 3 + 1];
        float v  = stds[a] * stds[a];
        float rv = FAST_RCP(v);
        float z  = -0.72134752044448f * rv;                 // -0.5*log2(e)/var
        float w  = __log2f(dens[a] * 0.15915494309189535f * rv);
        sh.sG[i] = make_float4(x, y, z, w);
    }
    __syncthreads();

    const int nc = cnt >> 5;          // chunks of 32 atoms: 20 or 5

    // GEN role: wave -> (axis, 4-atom group); positions = lane, lane+64
    const int gaxis = wav >> 3;       // 0 = gx (cols), 1 = gy (rows)
    const int agrp  = wav & 7;        // 8 groups x 4 atoms = 32 atoms
    const float c0  = (float)lane - 63.5f;

    // compute role: tile (r = wav>>2, c = wav&3); frag rows/cols per lane
    const int arow = (wav >> 2) * 32 + l31;   // gy row
    const int bcol = (wav & 3) * 32 + l31;    // gx col
    const int koff = hi * 8;                  // K-step atom sub-offset

    floatx16 acc = (floatx16){0.f};

    // compute chunk c's 8 values (4 atoms x 2 positions) into regs
    auto GEN_COMPUTE = [&](int c, half4_u& V0, half4_u& V1) {
        const float4* prm = &sh.sG[c * KC + agrp * 4];   // wave-uniform bcast
#pragma unroll
        for (int i2 = 0; i2 < 2; ++i2) {
            float e0[2], e1[2];
#pragma unroll
            for (int u = 0; u < 2; ++u) {
                float4 p = prm[i2 * 2 + u];      // (x, y, z, w)
                float mu = gaxis ? p.y : p.x;
                float wc = gaxis ? p.w : 0.0f;   // gx carries no coef
                float d  = c0 - mu;
                float t  = p.z * d;
                float g0 = fmaf(t, d, wc);
                float g1 = fmaf(128.0f, t, fmaf(4096.0f, p.z, g0));  // pos +64
                e0[u] = FAST_EXP2(g0);
                e1[u] = FAST_EXP2(g1);
            }
            V0.h[i2] = PKRTZ(e0[0], e0[1]);
            V1.h[i2] = PKRTZ(e1[0], e1[1]);
        }
    };

    // STEP: consume chunk c from parity P; generate chunk c+1 into P^1.
    // P^1 was fully consumed before the previous barrier -> safe pre-barrier.
#define STEP(P)                                                                \
    do {                                                                       \
        const f16* gy = sh.g[(P)][1];                                          \
        const f16* gx = sh.g[(P)][0];                                          \
        const bool gen = (c + 1 < nc);                                         \
        half4_u V0, V1;                                                        \
        if (gen) GEN_COMPUTE(c + 1, V0, V1);                                   \
        _Pragma("unroll")                                                      \
        for (int s = 0; s < 2; ++s) {                                          \
            frag_u Af, Bf;                                                     \
            Af.v = *(const f16x8*)(gy + arow * GSTR + s * 16 + koff);          \
            Bf.v = *(const f16x8*)(gx + bcol * GSTR + s * 16 + koff);          \
            acc = __builtin_amdgcn_mfma_f32_32x32x16_f16(Af.v, Bf.v, acc, 0, 0, 0); \
        }                                                                      \
        if (gen) {                                                             \
            f16* dst = &sh.g[(P) ^ 1][gaxis][lane * GSTR + agrp * 4];          \
            *(f16x4*)dst               = V0.q;                                 \
            *(f16x4*)(dst + 64 * GSTR) = V1.q;                                 \
        }                                                                      \
        __syncthreads();                                                       \
        ++c;                                                                   \
    } while (0)

    {   // prologue: chunk 0 into parity 0
        half4_u V0, V1;
        GEN_COMPUTE(0, V0, V1);
        f16* dst = &sh.g[0][gaxis][lane * GSTR + agrp * 4];
        *(f16x4*)dst               = V0.q;
        *(f16x4*)(dst + 64 * GSTR) = V1.q;
    }
    __syncthreads();

    int c = 0;
    while (c + 2 <= nc) { STEP(0); STEP(1); }
    if (c < nc) STEP(0);              // nc odd (tail split): even parity
#undef STEP

    // epilogue: direct store -- wave owns tile wav completely (full K summed)
    {
        f16* pq = part + ((size_t)(b * NS + ks)) * (S * S)
                       + (size_t)wav * 1024 + lane * 16;
        frag_u lo, hiv;
#pragma unroll
        for (int jp = 0; jp < 4; ++jp) {
            lo.h[jp]  = PKRTZ(acc[2 * jp],     acc[2 * jp + 1]);
            hiv.h[jp] = PKRTZ(acc[2 * jp + 8], acc[2 * jp + 9]);
        }
        *(f16x8*)(pq + 0) = lo.v;
        *(f16x8*)(pq + 8) = hiv.v;
    }
}

// sum NS f16 partials per batch: 4 waves/block each sum 8 slices (512 blocks),
// LDS combine, un-permute fragment order, write f32.
__global__ __launch_bounds__(256) void k_reduce(const f16* __restrict__ part,
                                                float* __restrict__ out) {
    __shared__ float lred[3][64][9];   // +1 pad: conflict-free strided stores
    const int b    = blockIdx.z;
    const int lane = threadIdx.x & 63;
    const int w    = threadIdx.x >> 6;
    const int f8   = (blockIdx.x * 64 + lane) * 8;   // frag-order base idx

    const f16* src = part + (size_t)b * NS * (S * S) + (size_t)(w * 8) * (S * S) + f8;
    float s[8] = {0.f};
#pragma unroll
    for (int t = 0; t < 8; ++t) {
        f16x8 v = *(const f16x8*)&src[(size_t)t * (S * S)];
#pragma unroll
        for (int i = 0; i < 8; ++i) s[i] += (float)v[i];
    }

    if (w) {
#pragma unroll
        for (int i = 0; i < 8; ++i) lred[w - 1][lane][i] = s[i];
    }
    __syncthreads();

    if (w == 0) {
#pragma unroll
        for (int j = 0; j < 3; ++j)
#pragma unroll
            for (int i = 0; i < 8; ++i) s[i] += lred[j][lane][i];

        // decode f8 = tile*1024 + lane_f*16 + reg0; tile = r*4 + c (32x32 tiles)
        const int reg0   = f8 & 15;
        const int lane_f = (f8 >> 4) & 63;
        const int tile   = f8 >> 10;
        const int r      = tile >> 2;
        const int cc     = tile & 3;
        // mfma_32x32 C/D: col = lane&31, row = (reg&3) + 8*(reg>>2) + 4*(lane>>5)
        const int rowb = r * 32 + 4 * (lane_f >> 5);
        const int col  = cc * 32 + (lane_f & 31);
#pragma unroll
        for (int i = 0; i < 8; ++i) {
            const int reg = reg0 + i;
            const int row = rowb + (reg & 3) + 8 * (reg >> 2);
            out[((size_t)b * S + row) * S + col] = s[i];
        }
    }
}

extern "C" void kernel_launch(void* const* d_in, const int* in_sizes, int n_in,
                              void* d_out, int out_size, void* d_ws, size_t ws_size,
                              hipStream_t stream) {
    const float* mol  = (const float*)d_in[0];
    const float* stds = (const float*)d_in[1];
    const float* dens = (const float*)d_in[2];
    float* out = (float*)d_out;

    const int A = in_sizes[1];             // 20000
    const int B = in_sizes[0] / (A * 3);   // 16

    f16* part = (f16*)d_ws;                // B*NS*16384*2 = 16 MB

    k_proj<<<dim3(NS, B), dim3(BLOCK), 0, stream>>>(mol, stds, dens, part, B, A);
    k_reduce<<<dim3((S * S) / (64 * 8), 1, B), dim3(256), 0, stream>>>(part, out);
}